// Round 1
// baseline (965.182 us; speedup 1.0000x reference)
//
#include <hip/hip_runtime.h>
#include <hip/hip_bf16.h>

#define N_REL 8

typedef unsigned short ushort_t;
typedef unsigned int uint_t;
typedef __attribute__((ext_vector_type(8))) short short8;   // bf16x8 MFMA operand
typedef __attribute__((ext_vector_type(4))) float floatx4;  // MFMA accumulator

static __device__ __forceinline__ ushort_t f2bf(float f) {
    union { float f; unsigned u; } v; v.f = f;
    unsigned r = v.u + 0x7fff + ((v.u >> 16) & 1);
    return (ushort_t)(r >> 16);
}

typedef __attribute__((address_space(1))) void glob_void;
typedef __attribute__((address_space(3))) void lds_void;

static __device__ __forceinline__ void load_lds16(const void* g, void* l) {
    __builtin_amdgcn_global_load_lds((glob_void*)g, (lds_void*)l, 16, 0, 0);
}

// Stage one 128x64 bf16 half-tile (16 KB) from global [rows][K] into LDS, linear
// [r][chunk] layout, with the st-swizzle (chunk ^= r&7) pre-applied on the GLOBAL
// source address (global_load_lds writes wave-uniform-base + lane*16 only).
// 2 global_load_lds per thread (512 threads x 2 x 16B = 16 KB).
static __device__ __forceinline__ void stage_half(const ushort_t* __restrict__ g,
                                                  int row0, int rmax, int K, int k0,
                                                  ushort_t* lds, int w, int l) {
    const int rl = l >> 3;
    const int gc = ((l & 7) ^ rl) * 8;  // swizzled 16B chunk within the row
#pragma unroll
    for (int s = 0; s < 2; ++s) {
        int r = row0 + s * 64 + w * 8 + rl;
        r = r < rmax ? r : rmax - 1;  // clamp (stores are guarded; dup rows harmless)
        load_lds16(g + (size_t)r * K + k0 + gc, lds + (s * 64 + w * 8) * 64);
    }
}

// ---------------- sort infrastructure ----------------

__global__ __launch_bounds__(256) void hist_kernel(const int* __restrict__ dst,
                                                   const int* __restrict__ et,
                                                   int* __restrict__ cnt, int E) {
    int e = blockIdx.x * blockDim.x + threadIdx.x;
    if (e < E) atomicAdd(&cnt[dst[e] * N_REL + et[e]], 1);
}

__global__ __launch_bounds__(256) void scan1(const int* __restrict__ cnt,
                                             int* __restrict__ off,
                                             int* __restrict__ bsum, int nk) {
    __shared__ int s[256];
    int t = threadIdx.x;
    int k = blockIdx.x * 256 + t;
    int v = k < nk ? cnt[k] : 0;
    s[t] = v; __syncthreads();
    for (int d = 1; d < 256; d <<= 1) {
        int x = (t >= d) ? s[t - d] : 0;
        __syncthreads(); s[t] += x; __syncthreads();
    }
    if (k < nk) off[k] = s[t] - v;
    if (t == 255) bsum[blockIdx.x] = s[255];
}

__global__ __launch_bounds__(1024) void scan2(int* __restrict__ bsum, int nb) {
    __shared__ int s[1024];
    int t = threadIdx.x;
    int v = t < nb ? bsum[t] : 0;
    s[t] = v; __syncthreads();
    for (int d = 1; d < 1024; d <<= 1) {
        int x = (t >= d) ? s[t - d] : 0;
        __syncthreads(); s[t] += x; __syncthreads();
    }
    if (t < nb) bsum[t] = s[t] - v;
}

__global__ __launch_bounds__(256) void scan3(int* __restrict__ off,
                                             const int* __restrict__ bsum,
                                             int* __restrict__ cursor,
                                             int nk) {
    int k = blockIdx.x * 256 + threadIdx.x;
    if (k >= nk) return;
    int o = off[k] + bsum[k >> 8];
    off[k] = o;
    cursor[k] = o;
}

__global__ __launch_bounds__(256) void scatter_ids(const int* __restrict__ dst,
                                                   const int* __restrict__ et,
                                                   int* __restrict__ cursor,
                                                   int* __restrict__ eid, int E) {
    int e = blockIdx.x * blockDim.x + threadIdx.x;
    if (e < E) {
        int key = dst[e] * N_REL + et[e];
        int pos = atomicAdd(&cursor[key], 1);
        eid[pos] = e;
    }
}

// ---------------- casts ----------------

__global__ __launch_bounds__(256) void cast_bf16(const float* __restrict__ in,
                                                 ushort_t* __restrict__ out, long n) {
    long idx = ((long)blockIdx.x * blockDim.x + threadIdx.x) * 4;
    if (idx + 4 <= n) {
        float4 v = *(const float4*)(in + idx);
        ushort_t o[4] = {f2bf(v.x), f2bf(v.y), f2bf(v.z), f2bf(v.w)};
        *(uint2*)(out + idx) = *(const uint2*)o;
    } else {
        for (; idx < n; ++idx) out[idx] = f2bf(in[idx]);
    }
}

__global__ __launch_bounds__(256) void relu_cast_bf16(const float* __restrict__ in,
                                                      ushort_t* __restrict__ out, long n) {
    long idx = ((long)blockIdx.x * blockDim.x + threadIdx.x) * 4;
    if (idx + 4 <= n) {
        float4 v = *(const float4*)(in + idx);
        ushort_t o[4] = {f2bf(fmaxf(v.x, 0.f)), f2bf(fmaxf(v.y, 0.f)),
                         f2bf(fmaxf(v.z, 0.f)), f2bf(fmaxf(v.w, 0.f))};
        *(uint2*)(out + idx) = *(const uint2*)o;
    } else {
        for (; idx < n; ++idx) out[idx] = f2bf(fmaxf(in[idx], 0.f));
    }
}

// in: [z][K][N] fp32 -> out: [z][N][K] bf16.
__global__ __launch_bounds__(256) void transpose_cast(const float* __restrict__ in,
                                                      ushort_t* __restrict__ out,
                                                      int K, int N) {
    __shared__ float tile[32][33];
    const float* inp = in + (size_t)blockIdx.z * K * N;
    ushort_t* outp = out + (size_t)blockIdx.z * K * N;
    int n0 = blockIdx.x * 32, k0 = blockIdx.y * 32;
    int tx = threadIdx.x & 31, ty = threadIdx.x >> 5;
#pragma unroll
    for (int s = 0; s < 4; ++s)
        tile[ty + 8 * s][tx] = inp[(size_t)(k0 + ty + 8 * s) * N + n0 + tx];
    __syncthreads();
#pragma unroll
    for (int s = 0; s < 4; ++s)
        outp[(size_t)(n0 + ty + 8 * s) * K + k0 + tx] = f2bf(tile[tx][ty + 8 * s]);
}

// ---------------- 256x256 8-phase MFMA GEMM: C[M,N] = A[M,K] @ Bt[N,K]^T (+bias) ---
// Plain-HIP port of the verified 8-phase template (T2 st-swizzle + T3/T4 counted
// vmcnt + T5 setprio). 512 threads = 8 waves (2M x 4N), BK=64, LDS = 2 x (A 32K +
// B 32K) = 128 KiB, per-wave output 128x64 (rows interleaved: wm owns {wm*64,
// 128+wm*64}; cols: wn owns {wn*32, 128+wn*32}) so each LDS half-tile is consumed
// in exactly one phase and can be restaged one phase later (region-safe).
// Per K-tile: 4 phases = C-quadrants (qm,qn); one half-tile staged per phase;
// one vmcnt(6) per K-tile (phase 4) retires exactly the next tile's 4 half-tiles.

#define STAGE_A(b, h, ktx) stage_half(A, bm + (h) * 128, M, K, ((ktx) << 6), &sh.st[(b)][0][(h)][0], w, l)
#define STAGE_B(b, h, ktx) stage_half(Bt, bn + (h) * 128, N, K, ((ktx) << 6), &sh.st[(b)][1][(h)][0], w, l)

#define LOAD_A(b, qm)                                                          \
    {                                                                          \
        const ushort_t* pa_ = &sh.st[(b)][0][(qm)][0];                         \
        _Pragma("unroll") for (int i_ = 0; i_ < 4; ++i_) {                     \
            const int r_ = wm * 64 + i_ * 16 + l16;                            \
            _Pragma("unroll") for (int kk_ = 0; kk_ < 2; ++kk_) {              \
                const int ch_ = (kk_ * 4 + quad) ^ (r_ & 7);                   \
                areg[i_][kk_] = *(const short8*)&pa_[r_ * 64 + ch_ * 8];       \
            }                                                                  \
        }                                                                      \
    }

#define LOAD_B(b, qn)                                                          \
    {                                                                          \
        const ushort_t* pb_ = &sh.st[(b)][1][(qn)][0];                         \
        _Pragma("unroll") for (int j_ = 0; j_ < 2; ++j_) {                     \
            const int r_ = wn * 32 + j_ * 16 + l16;                            \
            _Pragma("unroll") for (int kk_ = 0; kk_ < 2; ++kk_) {              \
                const int ch_ = (kk_ * 4 + quad) ^ (r_ & 7);                   \
                breg[(qn)][j_][kk_] = *(const short8*)&pb_[r_ * 64 + ch_ * 8]; \
            }                                                                  \
        }                                                                      \
    }

#define MFMA_Q(qm, qn)                                                              \
    _Pragma("unroll") for (int i_ = 0; i_ < 4; ++i_)                                \
        _Pragma("unroll") for (int j_ = 0; j_ < 2; ++j_)                            \
            _Pragma("unroll") for (int kk_ = 0; kk_ < 2; ++kk_)                     \
                acc[(qm)][(qn)][i_][j_] = __builtin_amdgcn_mfma_f32_16x16x32_bf16(  \
                    areg[i_][kk_], breg[(qn)][j_][kk_], acc[(qm)][(qn)][i_][j_], 0, 0, 0);

#define PHASE_SYNC()                                                           \
    __builtin_amdgcn_s_barrier();                                              \
    asm volatile("s_waitcnt lgkmcnt(0)" ::: "memory");                         \
    __builtin_amdgcn_sched_barrier(0)

#define WINDOW(kt, b)                                                          \
    {                                                                          \
        /* phase 1: quadrant (0,0) — reads Ah0, Bh0 */                         \
        LOAD_A(b, 0);                                                          \
        LOAD_B(b, 0);                                                          \
        if ((kt) + 1 < nkt) STAGE_A((b) ^ 1, 1, (kt) + 1);                     \
        PHASE_SYNC();                                                          \
        __builtin_amdgcn_s_setprio(1);                                         \
        MFMA_Q(0, 0);                                                          \
        __builtin_amdgcn_s_setprio(0);                                         \
        __builtin_amdgcn_s_barrier();                                          \
        /* phase 2: quadrant (0,1) — reads Bh1; Ah0 now free */                \
        LOAD_B(b, 1);                                                          \
        if ((kt) + 2 < nkt) STAGE_A(b, 0, (kt) + 2);                           \
        PHASE_SYNC();                                                          \
        __builtin_amdgcn_s_setprio(1);                                         \
        MFMA_Q(0, 1);                                                          \
        __builtin_amdgcn_s_setprio(0);                                         \
        __builtin_amdgcn_s_barrier();                                          \
        /* phase 3: quadrant (1,0) — reads Ah1; Bh0 free */                    \
        LOAD_A(b, 1);                                                          \
        if ((kt) + 2 < nkt) STAGE_B(b, 0, (kt) + 2);                           \
        PHASE_SYNC();                                                          \
        __builtin_amdgcn_s_setprio(1);                                         \
        MFMA_Q(1, 0);                                                          \
        __builtin_amdgcn_s_setprio(0);                                         \
        __builtin_amdgcn_s_barrier();                                          \
        /* phase 4: quadrant (1,1) — no ds_reads; Bh1 free; counted vmcnt */   \
        if ((kt) + 2 < nkt) {                                                  \
            STAGE_B(b, 1, (kt) + 2);                                           \
            asm volatile("s_waitcnt vmcnt(6)" ::: "memory");                   \
        } else {                                                               \
            asm volatile("s_waitcnt vmcnt(0)" ::: "memory"); /* epilogue drain */ \
        }                                                                      \
        __builtin_amdgcn_s_barrier();                                          \
        __builtin_amdgcn_sched_barrier(0);                                     \
        __builtin_amdgcn_s_setprio(1);                                         \
        MFMA_Q(1, 1);                                                          \
        __builtin_amdgcn_s_setprio(0);                                         \
        __builtin_amdgcn_s_barrier();                                          \
    }

template <typename OutT>
__global__ __launch_bounds__(512, 2) void gemm256(const ushort_t* __restrict__ A,
                                                  const ushort_t* __restrict__ Bt,
                                                  const float* __restrict__ bias,
                                                  OutT* __restrict__ C,
                                                  int M, int K, int N) {
    __shared__ union {
        __align__(16) ushort_t st[2][2][2][128 * 64];  // [buf][A/B][half][r*64+c]
        __align__(16) ushort_t c[256 * 256];           // bf16 epilogue staging (128 KB)
    } sh;

    const int t = threadIdx.x;
    const int l = t & 63;
    const int w = t >> 6;
    const int wm = w >> 2, wn = w & 3;
    const int quad = l >> 4, l16 = l & 15;

    // bijective XCD-aware swizzle (m204): consecutive wgids land on one XCD
    const int nx = gridDim.x;
    const int nwg = nx * gridDim.y;
    const int orig = blockIdx.y * nx + blockIdx.x;
    const int q8 = nwg >> 3, r8 = nwg & 7;
    const int xcd = orig & 7;
    const int wgid = ((xcd < r8) ? xcd * (q8 + 1) : r8 * (q8 + 1) + (xcd - r8) * q8) + (orig >> 3);
    const int bm = (wgid / nx) * 256;
    const int bn = (wgid % nx) * 256;

    const int nkt = K >> 6;  // K-tiles of 64; K % 128 == 0 for all our shapes

    floatx4 acc[2][2][4][2];
#pragma unroll
    for (int a = 0; a < 2; ++a)
#pragma unroll
        for (int bq = 0; bq < 2; ++bq)
#pragma unroll
            for (int i = 0; i < 4; ++i)
#pragma unroll
                for (int j = 0; j < 2; ++j) acc[a][bq][i][j] = (floatx4)(0.f);

    short8 areg[4][2];
    short8 breg[2][2][2];

    // prologue: tile0 fully, tile1 all but Ah1; vmcnt(6) retires exactly tile0
    STAGE_A(0, 0, 0); STAGE_B(0, 0, 0); STAGE_B(0, 1, 0); STAGE_A(0, 1, 0);
    STAGE_A(1, 0, 1); STAGE_B(1, 0, 1); STAGE_B(1, 1, 1);
    asm volatile("s_waitcnt vmcnt(6)" ::: "memory");
    __builtin_amdgcn_s_barrier();

    for (int kt = 0; kt < nkt; kt += 2) {
        WINDOW(kt, 0);
        WINDOW(kt + 1, 1);
    }

    if constexpr (__is_same(OutT, ushort_t)) {
        __syncthreads();  // union transition: all LDS reads done before C staging
#pragma unroll
        for (int qm = 0; qm < 2; ++qm)
#pragma unroll
            for (int qn = 0; qn < 2; ++qn)
#pragma unroll
                for (int i = 0; i < 4; ++i)
#pragma unroll
                    for (int j = 0; j < 2; ++j) {
                        const int rl = qm * 128 + wm * 64 + i * 16 + quad * 4;
                        const int cl = qn * 128 + wn * 32 + j * 16 + l16;
                        const float bv = bias ? bias[bn + cl] : 0.f;
#pragma unroll
                        for (int rg = 0; rg < 4; ++rg)
                            sh.c[(rl + rg) * 256 + cl] = f2bf(acc[qm][qn][i][j][rg] + bv);
                    }
        __syncthreads();
#pragma unroll
        for (int sw = 0; sw < 16; ++sw) {
            const int idx = sw * 512 + t;
            const int row = idx >> 5;
            const int ch = (idx & 31) * 8;
            const int grow = bm + row;
            if (grow < M)
                *(uint4*)(C + (size_t)grow * N + bn + ch) = *(const uint4*)&sh.c[row * 256 + ch];
        }
    } else {
#pragma unroll
        for (int qm = 0; qm < 2; ++qm)
#pragma unroll
            for (int qn = 0; qn < 2; ++qn)
#pragma unroll
                for (int j = 0; j < 2; ++j) {
                    const int cl = qn * 128 + wn * 32 + j * 16 + l16;
                    const float bv = bias ? bias[bn + cl] : 0.f;
#pragma unroll
                    for (int i = 0; i < 4; ++i) {
                        const int row0 = bm + qm * 128 + wm * 64 + i * 16 + quad * 4;
#pragma unroll
                        for (int rg = 0; rg < 4; ++rg) {
                            const int row = row0 + rg;
                            if (row < M) C[(size_t)row * N + (bn + cl)] = acc[qm][qn][i][j][rg] + bv;
                        }
                    }
                }
    }
}

#undef STAGE_A
#undef STAGE_B
#undef LOAD_A
#undef LOAD_B
#undef MFMA_Q
#undef PHASE_SYNC
#undef WINDOW

// ---------------- fused multi-relation segmented mean (no atomics) ----------------
__global__ __launch_bounds__(256) void segsum_multi(const ushort_t* __restrict__ H,
                                                    float* __restrict__ agg,
                                                    const int* __restrict__ off,
                                                    const int* __restrict__ cnt,
                                                    const int* __restrict__ eid,
                                                    const int* __restrict__ src,
                                                    int rbase, int rcount,
                                                    int dim, int hstride) {
    int d = blockIdx.x;
    int t = threadIdx.x;
    float a0 = 0.f, a1 = 0.f;
    bool any = false;
    for (int rr = 0; rr < rcount; ++rr) {
        int key = d * N_REL + rbase + rr;
        int c = cnt[key];
        if (c == 0) continue;
        any = true;
        int o = off[key];
        float s0 = 0.f, s1 = 0.f;
        const ushort_t* Hr = H + rr * dim + 2 * t;
        for (int k = o; k < o + c; ++k) {
            int e = eid[k];
            int s = src[e];
            uint_t u = *(const uint_t*)(Hr + (size_t)s * hstride);
            s0 += __uint_as_float(u << 16);
            s1 += __uint_as_float(u & 0xffff0000u);
        }
        float inv = 1.0f / (float)c;
        a0 += s0 * inv;
        a1 += s1 * inv;
    }
    if (!any) return;
    float2* p = (float2*)(agg + (size_t)d * dim + 2 * t);
    float2 g = *p;
    g.x += a0;
    g.y += a1;
    *p = g;
}

// ---------------- launcher ----------------

extern "C" void kernel_launch(void* const* d_in, const int* in_sizes, int n_in,
                              void* d_out, int out_size, void* d_ws, size_t ws_size,
                              hipStream_t stream) {
    const float* x     = (const float*)d_in[0];
    const int*   eidx  = (const int*)d_in[1];
    const int*   etype = (const int*)d_in[2];
    const float* W1    = (const float*)d_in[3];
    const float* root1 = (const float*)d_in[4];
    const float* b1    = (const float*)d_in[5];
    const float* W2    = (const float*)d_in[6];
    const float* root2 = (const float*)d_in[7];
    const float* b2    = (const float*)d_in[8];
    float* out = (float*)d_out;

    const int IN_DIM = 1280, HID_DIM = 512, OUT_DIM = 256;
    const int E = in_sizes[2];
    const int N = in_sizes[0] / IN_DIM;
    const int NK = N * N_REL;
    const int* srcs = eidx;
    const int* dsts = eidx + E;

    char* ws = (char*)d_ws;
    size_t offb = 0;
    auto alloc = [&](size_t bytes) { void* p = ws + offb; offb += (bytes + 255) & ~(size_t)255; return p; };
    int*      cnt    = (int*)alloc((size_t)NK * 4);
    int*      off    = (int*)alloc((size_t)NK * 4);
    int*      cursor = (int*)alloc((size_t)NK * 4);
    int*      bsum   = (int*)alloc(1024 * 4);
    int*      eid    = (int*)alloc((size_t)E * 4);
    ushort_t* x_bf   = (ushort_t*)alloc((size_t)N * IN_DIM * 2);   // later reused for hb_bf
    ushort_t* W1t    = (ushort_t*)alloc((size_t)N_REL * IN_DIM * HID_DIM * 2);
    ushort_t* r1t    = (ushort_t*)alloc((size_t)IN_DIM * HID_DIM * 2);
    ushort_t* W2t    = (ushort_t*)alloc((size_t)N_REL * HID_DIM * OUT_DIM * 2);
    ushort_t* r2t    = (ushort_t*)alloc((size_t)HID_DIM * OUT_DIM * 2);
    ushort_t* Hb     = (ushort_t*)alloc((size_t)N * 1024 * 2);
    float*    hbuf   = (float*)alloc((size_t)N * HID_DIM * 4);
    ushort_t* hb_bf  = x_bf;  // x_bf dead after layer-1 GEMMs
    (void)ws_size;

    const int nb = (NK + 255) / 256;

    // 1) sort edges by (dst, rel)
    hipMemsetAsync(cnt, 0, (size_t)NK * 4, stream);
    hist_kernel<<<(E + 255) / 256, 256, 0, stream>>>(dsts, etype, cnt, E);
    scan1<<<nb, 256, 0, stream>>>(cnt, off, bsum, NK);
    scan2<<<1, 1024, 0, stream>>>(bsum, nb);
    scan3<<<nb, 256, 0, stream>>>(off, bsum, cursor, NK);
    scatter_ids<<<(E + 255) / 256, 256, 0, stream>>>(dsts, etype, cursor, eid, E);

    // 2) casts / weight transposes
    {
        long n = (long)N * IN_DIM;
        cast_bf16<<<(unsigned)((n / 4 + 255) / 256), 256, 0, stream>>>(x, x_bf, n);
    }
    transpose_cast<<<dim3(HID_DIM / 32, IN_DIM / 32, N_REL), 256, 0, stream>>>(W1, W1t, IN_DIM, HID_DIM);
    transpose_cast<<<dim3(HID_DIM / 32, IN_DIM / 32, 1), 256, 0, stream>>>(root1, r1t, IN_DIM, HID_DIM);
    transpose_cast<<<dim3(OUT_DIM / 32, HID_DIM / 32, N_REL), 256, 0, stream>>>(W2, W2t, HID_DIM, OUT_DIM);
    transpose_cast<<<dim3(OUT_DIM / 32, HID_DIM / 32, 1), 256, 0, stream>>>(root2, r2t, HID_DIM, OUT_DIM);

    const int mb = (N + 255) / 256;  // 256-row tiles; bijective swizzle needs no padding

    // 3) layer 1: root GEMM into fp32 hbuf, then 4 batches of 2 relations
    gemm256<float><<<dim3(HID_DIM / 256, mb), 512, 0, stream>>>(x_bf, r1t, b1, hbuf, N, IN_DIM, HID_DIM);
    for (int b = 0; b < 4; ++b) {
        const int RB = 2, NB = RB * HID_DIM;  // 1024
        gemm256<ushort_t><<<dim3(NB / 256, mb), 512, 0, stream>>>(
            x_bf, W1t + (size_t)b * RB * HID_DIM * IN_DIM, nullptr, Hb, N, IN_DIM, NB);
        segsum_multi<<<N, HID_DIM / 2, 0, stream>>>(Hb, hbuf, off, cnt, eid, srcs,
                                                    b * RB, RB, HID_DIM, NB);
    }
    {
        long n = (long)N * HID_DIM;
        relu_cast_bf16<<<(unsigned)((n / 4 + 255) / 256), 256, 0, stream>>>(hbuf, hb_bf, n);
    }

    // 4) layer 2: root GEMM into out, then 2 batches of 4 relations
    gemm256<float><<<dim3(OUT_DIM / 256, mb), 512, 0, stream>>>(hb_bf, r2t, b2, out, N, HID_DIM, OUT_DIM);
    for (int b = 0; b < 2; ++b) {
        const int RB = 4, NB = RB * OUT_DIM;  // 1024
        gemm256<ushort_t><<<dim3(NB / 256, mb), 512, 0, stream>>>(
            hb_bf, W2t + (size_t)b * RB * OUT_DIM * HID_DIM, nullptr, Hb, N, HID_DIM, NB);
        segsum_multi<<<N, OUT_DIM / 2, 0, stream>>>(Hb, out, off, cnt, eid, srcs,
                                                    b * RB, RB, OUT_DIM, NB);
    }
}

// Round 2
// 659.506 us; speedup vs baseline: 1.4635x; 1.4635x over previous
//
#include <hip/hip_runtime.h>
#include <hip/hip_bf16.h>

#define N_REL 8

typedef unsigned short ushort_t;
typedef unsigned int uint_t;
typedef __attribute__((ext_vector_type(8))) short short8;   // bf16x8 MFMA operand
typedef __attribute__((ext_vector_type(4))) float floatx4;  // MFMA accumulator

static __device__ __forceinline__ ushort_t f2bf(float f) {
    union { float f; unsigned u; } v; v.f = f;
    unsigned r = v.u + 0x7fff + ((v.u >> 16) & 1);
    return (ushort_t)(r >> 16);
}

typedef __attribute__((address_space(1))) void glob_void;
typedef __attribute__((address_space(3))) void lds_void;

static __device__ __forceinline__ void load_lds16(const void* g, void* l) {
    __builtin_amdgcn_global_load_lds((glob_void*)g, (lds_void*)l, 16, 0, 0);
}

// Stage one 128x64 bf16 half-tile (16 KB) from global [rows][K] into LDS, linear
// [r][chunk] layout, with the st-swizzle (chunk ^= r&7) pre-applied on the GLOBAL
// source address (global_load_lds writes wave-uniform-base + lane*16 only).
static __device__ __forceinline__ void stage_half(const ushort_t* __restrict__ g,
                                                  int row0, int rmax, int K, int k0,
                                                  ushort_t* lds, int w, int l) {
    const int rl = l >> 3;
    const int gc = ((l & 7) ^ rl) * 8;  // swizzled 16B chunk within the row
#pragma unroll
    for (int s = 0; s < 2; ++s) {
        int r = row0 + s * 64 + w * 8 + rl;
        r = r < rmax ? r : rmax - 1;  // clamp (stores are guarded; dup rows harmless)
        load_lds16(g + (size_t)r * K + k0 + gc, lds + (s * 64 + w * 8) * 64);
    }
}

// ---------------- sort infrastructure ----------------

__global__ __launch_bounds__(256) void hist_kernel(const int* __restrict__ dst,
                                                   const int* __restrict__ et,
                                                   int* __restrict__ cnt, int E) {
    int e = blockIdx.x * blockDim.x + threadIdx.x;
    if (e < E) atomicAdd(&cnt[dst[e] * N_REL + et[e]], 1);
}

__global__ __launch_bounds__(256) void scan1(const int* __restrict__ cnt,
                                             int* __restrict__ off,
                                             int* __restrict__ bsum, int nk) {
    __shared__ int s[256];
    int t = threadIdx.x;
    int k = blockIdx.x * 256 + t;
    int v = k < nk ? cnt[k] : 0;
    s[t] = v; __syncthreads();
    for (int d = 1; d < 256; d <<= 1) {
        int x = (t >= d) ? s[t - d] : 0;
        __syncthreads(); s[t] += x; __syncthreads();
    }
    if (k < nk) off[k] = s[t] - v;
    if (t == 255) bsum[blockIdx.x] = s[255];
}

__global__ __launch_bounds__(1024) void scan2(int* __restrict__ bsum, int nb) {
    __shared__ int s[1024];
    int t = threadIdx.x;
    int v = t < nb ? bsum[t] : 0;
    s[t] = v; __syncthreads();
    for (int d = 1; d < 1024; d <<= 1) {
        int x = (t >= d) ? s[t - d] : 0;
        __syncthreads(); s[t] += x; __syncthreads();
    }
    if (t < nb) bsum[t] = s[t] - v;
}

__global__ __launch_bounds__(256) void scan3(int* __restrict__ off,
                                             const int* __restrict__ bsum,
                                             int* __restrict__ cursor,
                                             int nk) {
    int k = blockIdx.x * 256 + threadIdx.x;
    if (k >= nk) return;
    int o = off[k] + bsum[k >> 8];
    off[k] = o;
    cursor[k] = o;
}

// stores src[e] directly (not e) — removes one dependent load in the gather loop
__global__ __launch_bounds__(256) void scatter_src(const int* __restrict__ dst,
                                                   const int* __restrict__ et,
                                                   const int* __restrict__ src,
                                                   int* __restrict__ cursor,
                                                   int* __restrict__ esrc, int E) {
    int e = blockIdx.x * blockDim.x + threadIdx.x;
    if (e < E) {
        int key = dst[e] * N_REL + et[e];
        int pos = atomicAdd(&cursor[key], 1);
        esrc[pos] = src[e];
    }
}

// ---------------- casts ----------------

__global__ __launch_bounds__(256) void cast_bf16(const float* __restrict__ in,
                                                 ushort_t* __restrict__ out, long n) {
    long idx = ((long)blockIdx.x * blockDim.x + threadIdx.x) * 4;
    if (idx + 4 <= n) {
        float4 v = *(const float4*)(in + idx);
        ushort_t o[4] = {f2bf(v.x), f2bf(v.y), f2bf(v.z), f2bf(v.w)};
        *(uint2*)(out + idx) = *(const uint2*)o;
    } else {
        for (; idx < n; ++idx) out[idx] = f2bf(in[idx]);
    }
}

// in: [z][K][N] fp32 -> out: [z][N][K] bf16.
__global__ __launch_bounds__(256) void transpose_cast(const float* __restrict__ in,
                                                      ushort_t* __restrict__ out,
                                                      int K, int N) {
    __shared__ float tile[32][33];
    const float* inp = in + (size_t)blockIdx.z * K * N;
    ushort_t* outp = out + (size_t)blockIdx.z * K * N;
    int n0 = blockIdx.x * 32, k0 = blockIdx.y * 32;
    int tx = threadIdx.x & 31, ty = threadIdx.x >> 5;
#pragma unroll
    for (int s = 0; s < 4; ++s)
        tile[ty + 8 * s][tx] = inp[(size_t)(k0 + ty + 8 * s) * N + n0 + tx];
    __syncthreads();
#pragma unroll
    for (int s = 0; s < 4; ++s)
        outp[(size_t)(n0 + ty + 8 * s) * K + k0 + tx] = f2bf(tile[tx][ty + 8 * s]);
}

// ---------------- 256x256 8-phase MFMA GEMM: C[M,N] = A[M,K] @ Bt[N,K]^T ---------
// Verified 8-phase template (T2 st-swizzle + T3/T4 counted vmcnt + T5 setprio).
// 512 threads = 8 waves (2M x 4N), BK=64, LDS = 128 KiB double-buffered.
// Per K-tile: 4 phases = C-quadrants; one half-tile staged per phase; one
// vmcnt(6) per K-tile retires exactly the next tile's 4 half-tiles.

#define STAGE_A(b, h, ktx) stage_half(A, bm + (h) * 128, M, K, ((ktx) << 6), &sh.st[(b)][0][(h)][0], w, l)
#define STAGE_B(b, h, ktx) stage_half(Bt, bn + (h) * 128, N, K, ((ktx) << 6), &sh.st[(b)][1][(h)][0], w, l)

#define LOAD_A(b, qm)                                                          \
    {                                                                          \
        const ushort_t* pa_ = &sh.st[(b)][0][(qm)][0];                         \
        _Pragma("unroll") for (int i_ = 0; i_ < 4; ++i_) {                     \
            const int r_ = wm * 64 + i_ * 16 + l16;                            \
            _Pragma("unroll") for (int kk_ = 0; kk_ < 2; ++kk_) {              \
                const int ch_ = (kk_ * 4 + quad) ^ (r_ & 7);                   \
                areg[i_][kk_] = *(const short8*)&pa_[r_ * 64 + ch_ * 8];       \
            }                                                                  \
        }                                                                      \
    }

#define LOAD_B(b, qn)                                                          \
    {                                                                          \
        const ushort_t* pb_ = &sh.st[(b)][1][(qn)][0];                         \
        _Pragma("unroll") for (int j_ = 0; j_ < 2; ++j_) {                     \
            const int r_ = wn * 32 + j_ * 16 + l16;                            \
            _Pragma("unroll") for (int kk_ = 0; kk_ < 2; ++kk_) {              \
                const int ch_ = (kk_ * 4 + quad) ^ (r_ & 7);                   \
                breg[(qn)][j_][kk_] = *(const short8*)&pb_[r_ * 64 + ch_ * 8]; \
            }                                                                  \
        }                                                                      \
    }

#define MFMA_Q(qm, qn)                                                              \
    _Pragma("unroll") for (int i_ = 0; i_ < 4; ++i_)                                \
        _Pragma("unroll") for (int j_ = 0; j_ < 2; ++j_)                            \
            _Pragma("unroll") for (int kk_ = 0; kk_ < 2; ++kk_)                     \
                acc[(qm)][(qn)][i_][j_] = __builtin_amdgcn_mfma_f32_16x16x32_bf16(  \
                    areg[i_][kk_], breg[(qn)][j_][kk_], acc[(qm)][(qn)][i_][j_], 0, 0, 0);

#define PHASE_SYNC()                                                           \
    __builtin_amdgcn_s_barrier();                                              \
    asm volatile("s_waitcnt lgkmcnt(0)" ::: "memory");                         \
    __builtin_amdgcn_sched_barrier(0)

#define WINDOW(kt, b)                                                          \
    {                                                                          \
        /* phase 1: quadrant (0,0) — reads Ah0, Bh0 */                         \
        LOAD_A(b, 0);                                                          \
        LOAD_B(b, 0);                                                          \
        if ((kt) + 1 < nkt) STAGE_A((b) ^ 1, 1, (kt) + 1);                     \
        PHASE_SYNC();                                                          \
        __builtin_amdgcn_s_setprio(1);                                         \
        MFMA_Q(0, 0);                                                          \
        __builtin_amdgcn_s_setprio(0);                                         \
        __builtin_amdgcn_s_barrier();                                          \
        /* phase 2: quadrant (0,1) — reads Bh1; Ah0 now free */                \
        LOAD_B(b, 1);                                                          \
        if ((kt) + 2 < nkt) STAGE_A(b, 0, (kt) + 2);                           \
        PHASE_SYNC();                                                          \
        __builtin_amdgcn_s_setprio(1);                                         \
        MFMA_Q(0, 1);                                                          \
        __builtin_amdgcn_s_setprio(0);                                         \
        __builtin_amdgcn_s_barrier();                                          \
        /* phase 3: quadrant (1,0) — reads Ah1; Bh0 free */                    \
        LOAD_A(b, 1);                                                          \
        if ((kt) + 2 < nkt) STAGE_B(b, 0, (kt) + 2);                           \
        PHASE_SYNC();                                                          \
        __builtin_amdgcn_s_setprio(1);                                         \
        MFMA_Q(1, 0);                                                          \
        __builtin_amdgcn_s_setprio(0);                                         \
        __builtin_amdgcn_s_barrier();                                          \
        /* phase 4: quadrant (1,1) — no ds_reads; Bh1 free; counted vmcnt */   \
        if ((kt) + 2 < nkt) {                                                  \
            STAGE_B(b, 1, (kt) + 2);                                           \
            asm volatile("s_waitcnt vmcnt(6)" ::: "memory");                   \
        } else {                                                               \
            asm volatile("s_waitcnt vmcnt(0)" ::: "memory"); /* epilogue drain */ \
        }                                                                      \
        __builtin_amdgcn_s_barrier();                                          \
        __builtin_amdgcn_sched_barrier(0);                                     \
        __builtin_amdgcn_s_setprio(1);                                         \
        MFMA_Q(1, 1);                                                          \
        __builtin_amdgcn_s_setprio(0);                                         \
        __builtin_amdgcn_s_barrier();                                          \
    }

template <typename OutT>
__global__ __launch_bounds__(512, 2) void gemm256(const ushort_t* __restrict__ A,
                                                  const ushort_t* __restrict__ Bt,
                                                  const float* __restrict__ bias,
                                                  OutT* __restrict__ C,
                                                  int M, int K, int N) {
    __shared__ union {
        __align__(16) ushort_t st[2][2][2][128 * 64];  // [buf][A/B][half][r*64+c]
        __align__(16) ushort_t c[256 * 256];           // bf16 epilogue staging (128 KB)
    } sh;

    const int t = threadIdx.x;
    const int l = t & 63;
    const int w = t >> 6;
    const int wm = w >> 2, wn = w & 3;
    const int quad = l >> 4, l16 = l & 15;

    // bijective XCD-aware swizzle (m204): consecutive wgids land on one XCD
    const int nx = gridDim.x;
    const int nwg = nx * gridDim.y;
    const int orig = blockIdx.y * nx + blockIdx.x;
    const int q8 = nwg >> 3, r8 = nwg & 7;
    const int xcd = orig & 7;
    const int wgid = ((xcd < r8) ? xcd * (q8 + 1) : r8 * (q8 + 1) + (xcd - r8) * q8) + (orig >> 3);
    const int bm = (wgid / nx) * 256;
    const int bn = (wgid % nx) * 256;

    const int nkt = K >> 6;  // K-tiles of 64; K % 128 == 0 for all our shapes

    floatx4 acc[2][2][4][2];
#pragma unroll
    for (int a = 0; a < 2; ++a)
#pragma unroll
        for (int bq = 0; bq < 2; ++bq)
#pragma unroll
            for (int i = 0; i < 4; ++i)
#pragma unroll
                for (int j = 0; j < 2; ++j) acc[a][bq][i][j] = (floatx4)(0.f);

    short8 areg[4][2];
    short8 breg[2][2][2];

    // prologue: tile0 fully, tile1 all but Ah1; vmcnt(6) retires exactly tile0
    STAGE_A(0, 0, 0); STAGE_B(0, 0, 0); STAGE_B(0, 1, 0); STAGE_A(0, 1, 0);
    STAGE_A(1, 0, 1); STAGE_B(1, 0, 1); STAGE_B(1, 1, 1);
    asm volatile("s_waitcnt vmcnt(6)" ::: "memory");
    __builtin_amdgcn_s_barrier();

    for (int kt = 0; kt < nkt; kt += 2) {
        WINDOW(kt, 0);
        WINDOW(kt + 1, 1);
    }

    if constexpr (__is_same(OutT, ushort_t)) {
        __syncthreads();  // union transition: all LDS reads done before C staging
#pragma unroll
        for (int qm = 0; qm < 2; ++qm)
#pragma unroll
            for (int qn = 0; qn < 2; ++qn)
#pragma unroll
                for (int i = 0; i < 4; ++i)
#pragma unroll
                    for (int j = 0; j < 2; ++j) {
                        const int rl = qm * 128 + wm * 64 + i * 16 + quad * 4;
                        const int cl = qn * 128 + wn * 32 + j * 16 + l16;
                        const float bv = bias ? bias[bn + cl] : 0.f;
#pragma unroll
                        for (int rg = 0; rg < 4; ++rg)
                            sh.c[(rl + rg) * 256 + cl] = f2bf(acc[qm][qn][i][j][rg] + bv);
                    }
        __syncthreads();
#pragma unroll
        for (int sw = 0; sw < 16; ++sw) {
            const int idx = sw * 512 + t;
            const int row = idx >> 5;
            const int ch = (idx & 31) * 8;
            const int grow = bm + row;
            if (grow < M)
                *(uint4*)(C + (size_t)grow * N + bn + ch) = *(const uint4*)&sh.c[row * 256 + ch];
        }
    } else {
#pragma unroll
        for (int qm = 0; qm < 2; ++qm)
#pragma unroll
            for (int qn = 0; qn < 2; ++qn)
#pragma unroll
                for (int j = 0; j < 2; ++j) {
                    const int cl = qn * 128 + wn * 32 + j * 16 + l16;
                    const float bv = bias ? bias[bn + cl] : 0.f;
#pragma unroll
                    for (int i = 0; i < 4; ++i) {
                        const int row0 = bm + qm * 128 + wm * 64 + i * 16 + quad * 4;
#pragma unroll
                        for (int rg = 0; rg < 4; ++rg) {
                            const int row = row0 + rg;
                            if (row < M) C[(size_t)row * N + (bn + cl)] = acc[qm][qn][i][j][rg] + bv;
                        }
                    }
                }
    }
}

#undef STAGE_A
#undef STAGE_B
#undef LOAD_A
#undef LOAD_B
#undef MFMA_Q
#undef PHASE_SYNC
#undef WINDOW

// ---------------- fully-fused segmented mean + root + bias (+relu/cast) ----------
// H layout per node row (stride hs): [0..dim) root output, [dim + r*dim + c] rel r.
// One block per dst node; 2 dims per thread.

__global__ __launch_bounds__(256) void segsum_l1(const ushort_t* __restrict__ H,
                                                 const float* __restrict__ bias,
                                                 const int* __restrict__ off,
                                                 const int* __restrict__ cnt,
                                                 const int* __restrict__ esrc,
                                                 ushort_t* __restrict__ out) {
    const int d = blockIdx.x;
    const int t = threadIdx.x;          // 256 threads, dim 512
    const int hs = (N_REL + 1) * 512;   // 4608
    const ushort_t* base = H + (size_t)d * hs + 2 * t;
    uint_t ur = *(const uint_t*)base;   // root part
    float2 bv = *(const float2*)(bias + 2 * t);
    float a0 = __uint_as_float(ur << 16) + bv.x;
    float a1 = __uint_as_float(ur & 0xffff0000u) + bv.y;
#pragma unroll
    for (int r = 0; r < N_REL; ++r) {
        int key = d * N_REL + r;
        int c = cnt[key];
        if (c == 0) continue;
        int o = off[key];
        const ushort_t* Hr = H + (r + 1) * 512 + 2 * t;
        float s0 = 0.f, s1 = 0.f;
        for (int k = o; k < o + c; ++k) {
            int s = esrc[k];
            uint_t u = *(const uint_t*)(Hr + (size_t)s * hs);
            s0 += __uint_as_float(u << 16);
            s1 += __uint_as_float(u & 0xffff0000u);
        }
        float inv = 1.0f / (float)c;
        a0 += s0 * inv;
        a1 += s1 * inv;
    }
    a0 = fmaxf(a0, 0.f);
    a1 = fmaxf(a1, 0.f);
    ushort_t o2[2] = {f2bf(a0), f2bf(a1)};
    *(uint_t*)(out + (size_t)d * 512 + 2 * t) = *(const uint_t*)o2;
}

__global__ __launch_bounds__(128) void segsum_l2(const ushort_t* __restrict__ H,
                                                 const float* __restrict__ bias,
                                                 const int* __restrict__ off,
                                                 const int* __restrict__ cnt,
                                                 const int* __restrict__ esrc,
                                                 float* __restrict__ out) {
    const int d = blockIdx.x;
    const int t = threadIdx.x;          // 128 threads, dim 256
    const int hs = (N_REL + 1) * 256;   // 2304
    const ushort_t* base = H + (size_t)d * hs + 2 * t;
    uint_t ur = *(const uint_t*)base;   // root part
    float2 bv = *(const float2*)(bias + 2 * t);
    float a0 = __uint_as_float(ur << 16) + bv.x;
    float a1 = __uint_as_float(ur & 0xffff0000u) + bv.y;
#pragma unroll
    for (int r = 0; r < N_REL; ++r) {
        int key = d * N_REL + r;
        int c = cnt[key];
        if (c == 0) continue;
        int o = off[key];
        const ushort_t* Hr = H + (r + 1) * 256 + 2 * t;
        float s0 = 0.f, s1 = 0.f;
        for (int k = o; k < o + c; ++k) {
            int s = esrc[k];
            uint_t u = *(const uint_t*)(Hr + (size_t)s * hs);
            s0 += __uint_as_float(u << 16);
            s1 += __uint_as_float(u & 0xffff0000u);
        }
        float inv = 1.0f / (float)c;
        a0 += s0 * inv;
        a1 += s1 * inv;
    }
    *(float2*)(out + (size_t)d * 256 + 2 * t) = make_float2(a0, a1);
}

// ---------------- launcher ----------------

extern "C" void kernel_launch(void* const* d_in, const int* in_sizes, int n_in,
                              void* d_out, int out_size, void* d_ws, size_t ws_size,
                              hipStream_t stream) {
    const float* x     = (const float*)d_in[0];
    const int*   eidx  = (const int*)d_in[1];
    const int*   etype = (const int*)d_in[2];
    const float* W1    = (const float*)d_in[3];
    const float* root1 = (const float*)d_in[4];
    const float* b1    = (const float*)d_in[5];
    const float* W2    = (const float*)d_in[6];
    const float* root2 = (const float*)d_in[7];
    const float* b2    = (const float*)d_in[8];
    float* out = (float*)d_out;

    const int IN_DIM = 1280, HID_DIM = 512, OUT_DIM = 256;
    const int E = in_sizes[2];
    const int N = in_sizes[0] / IN_DIM;
    const int NK = N * N_REL;
    const int* srcs = eidx;
    const int* dsts = eidx + E;

    char* ws = (char*)d_ws;
    size_t offb = 0;
    auto alloc = [&](size_t bytes) { void* p = ws + offb; offb += (bytes + 255) & ~(size_t)255; return p; };
    int*      cnt    = (int*)alloc((size_t)NK * 4);
    int*      off    = (int*)alloc((size_t)NK * 4);
    int*      cursor = (int*)alloc((size_t)NK * 4);
    int*      bsum   = (int*)alloc(1024 * 4);
    int*      esrc   = (int*)alloc((size_t)E * 4);
    ushort_t* x_bf   = (ushort_t*)alloc((size_t)N * IN_DIM * 2);   // reused as hb_bf later
    // concat [root1t | W1t]: rows 0..511 root, 512..4607 relations (contiguous)
    ushort_t* rW1t   = (ushort_t*)alloc((size_t)(N_REL + 1) * IN_DIM * HID_DIM * 2);
    ushort_t* r1t    = rW1t;
    ushort_t* W1t    = rW1t + (size_t)HID_DIM * IN_DIM;
    // concat [root2t | W2t]: rows 0..255 root, 256..2303 relations
    ushort_t* rW2t   = (ushort_t*)alloc((size_t)(N_REL + 1) * HID_DIM * OUT_DIM * 2);
    ushort_t* r2t    = rW2t;
    ushort_t* W2t    = rW2t + (size_t)OUT_DIM * HID_DIM;
    ushort_t* Hb     = (ushort_t*)alloc((size_t)N * (N_REL + 1) * HID_DIM * 2);  // 184 MB
    ushort_t* hb_bf  = x_bf;  // x_bf dead after layer-1 GEMM
    (void)ws_size;

    const int nb = (NK + 255) / 256;

    // 1) sort edges by (dst, rel); store src directly
    hipMemsetAsync(cnt, 0, (size_t)NK * 4, stream);
    hist_kernel<<<(E + 255) / 256, 256, 0, stream>>>(dsts, etype, cnt, E);
    scan1<<<nb, 256, 0, stream>>>(cnt, off, bsum, NK);
    scan2<<<1, 1024, 0, stream>>>(bsum, nb);
    scan3<<<nb, 256, 0, stream>>>(off, bsum, cursor, NK);
    scatter_src<<<(E + 255) / 256, 256, 0, stream>>>(dsts, etype, srcs, cursor, esrc, E);

    // 2) casts / weight transposes (into the concatenated Bt buffers)
    {
        long n = (long)N * IN_DIM;
        cast_bf16<<<(unsigned)((n / 4 + 255) / 256), 256, 0, stream>>>(x, x_bf, n);
    }
    transpose_cast<<<dim3(HID_DIM / 32, IN_DIM / 32, 1), 256, 0, stream>>>(root1, r1t, IN_DIM, HID_DIM);
    transpose_cast<<<dim3(HID_DIM / 32, IN_DIM / 32, N_REL), 256, 0, stream>>>(W1, W1t, IN_DIM, HID_DIM);
    transpose_cast<<<dim3(OUT_DIM / 32, HID_DIM / 32, 1), 256, 0, stream>>>(root2, r2t, HID_DIM, OUT_DIM);
    transpose_cast<<<dim3(OUT_DIM / 32, HID_DIM / 32, N_REL), 256, 0, stream>>>(W2, W2t, HID_DIM, OUT_DIM);

    const int mb = (N + 255) / 256;  // 256-row tiles; bijective swizzle needs no padding

    // 3) layer 1: ONE fused GEMM (root + all 8 relations, N=4608) -> segsum+relu+cast
    {
        const int NTOT = (N_REL + 1) * HID_DIM;  // 4608
        gemm256<ushort_t><<<dim3(NTOT / 256, mb), 512, 0, stream>>>(
            x_bf, rW1t, nullptr, Hb, N, IN_DIM, NTOT);
        segsum_l1<<<N, HID_DIM / 2, 0, stream>>>(Hb, b1, off, cnt, esrc, hb_bf);
    }

    // 4) layer 2: ONE fused GEMM (root + all 8 relations, N=2304) -> segsum -> out
    {
        const int NTOT = (N_REL + 1) * OUT_DIM;  // 2304
        gemm256<ushort_t><<<dim3(NTOT / 256, mb), 512, 0, stream>>>(
            hb_bf, rW2t, nullptr, Hb, N, HID_DIM, NTOT);
        segsum_l2<<<N, OUT_DIM / 2, 0, stream>>>(Hb, b2, off, cnt, esrc, out);
    }
}